// Round 5
// baseline (173.329 us; speedup 1.0000x reference)
//
#include <hip/hip_runtime.h>

// SATD loss: sum(|H8 @ (orig - pred)|) over [524288, 3, 8, 8] fp32 blocks.
// Memory-bound streaming: 805 MB read -> 1 scalar.
//
// R0-R4 established: access pattern (strided/contiguous/persistent) doesn't
// move BW (all ~5.2-5.5 TB/s). This round probes OCCUPANCY: minimal VGPR
// (<=64 via __launch_bounds__(256,8)) so 32 waves/CU are resident, grid=8192
// blocks = every wave slot on 256 CUs filled in one dispatch pass.
//
// FWHT-8 distributed across lanes: flat float4 index = block*16 + row*2 +
// colhalf, so a wave's 64 lanes hold 4 whole 8x8 blocks and the 8 rows of a
// block live in lane bits 1..3 -> row transform = 3 shfl_xor butterflies.
// abs-sum is invariant to Hadamard output ordering, matching the reference.

typedef float fvec4 __attribute__((ext_vector_type(4)));

__device__ __forceinline__ float fwht_abssum(fvec4 t, int lane) {
    #pragma unroll
    for (int m = 2; m <= 8; m <<= 1) {
        const bool hi = (lane & m) != 0;
        fvec4 p;
        p.x = __shfl_xor(t.x, m, 64);
        p.y = __shfl_xor(t.y, m, 64);
        p.z = __shfl_xor(t.z, m, 64);
        p.w = __shfl_xor(t.w, m, 64);
        fvec4 add = t + p;
        fvec4 sub = p - t;
        t = hi ? sub : add;
    }
    return fabsf(t.x) + fabsf(t.y) + fabsf(t.z) + fabsf(t.w);
}

__global__ __launch_bounds__(256, 8) void satd_loss_kernel(
        const fvec4* __restrict__ orig, const fvec4* __restrict__ pred,
        float* __restrict__ out, int n4) {
    const int tid = blockIdx.x * blockDim.x + threadIdx.x;
    const int total = gridDim.x * blockDim.x;     // 2097152
    const int lane = threadIdx.x & 63;

    float acc = 0.0f;

    // n4 = 25165824 = 12 * total; two independent pairs per iteration (4 loads
    // in flight), no guards needed.
    for (int i = tid; i < n4; i += 2 * total) {
        fvec4 a0 = orig[i];
        fvec4 b0 = pred[i];
        fvec4 a1 = orig[i + total];
        fvec4 b1 = pred[i + total];
        acc += fwht_abssum(a0 - b0, lane);
        acc += fwht_abssum(a1 - b1, lane);
    }

    // wave-64 reduction
    #pragma unroll
    for (int off = 32; off > 0; off >>= 1)
        acc += __shfl_down(acc, off, 64);

    __shared__ float wsum[4];
    const int wid = threadIdx.x >> 6;
    if (lane == 0) wsum[wid] = acc;
    __syncthreads();

    if (threadIdx.x == 0) {
        float s = wsum[0] + wsum[1] + wsum[2] + wsum[3];
        atomicAdd(out, s);
    }
}

extern "C" void kernel_launch(void* const* d_in, const int* in_sizes, int n_in,
                              void* d_out, int out_size, void* d_ws, size_t ws_size,
                              hipStream_t stream) {
    const fvec4* orig = (const fvec4*)d_in[0];
    const fvec4* pred = (const fvec4*)d_in[1];
    float* out = (float*)d_out;

    const int nelem = in_sizes[0];   // 524288*3*64 = 100663296 floats
    const int n4 = nelem / 4;        // 25165824 float4s

    // harness poisons d_out; zero it every call (graph-capturable memset node)
    (void)hipMemsetAsync(out, 0, sizeof(float) * (size_t)out_size, stream);

    const int block = 256;
    const int grid = 8192;           // 32 waves/CU x 256 CU, one dispatch pass

    satd_loss_kernel<<<grid, block, 0, stream>>>(orig, pred, out, n4);
}

// Round 6
// 153.487 us; speedup vs baseline: 1.1293x; 1.1293x over previous
//
#include <hip/hip_runtime.h>

// SATD loss: sum(|H8 @ (orig - pred)|) over [524288, 3, 8, 8] fp32 blocks.
// 805 MB read -> 1 scalar. R0-R5: register-load versions all stall at
// ~5.5 TB/s because VGPR-held loads cap in-flight bytes at ~4-5 KB/CU
// (need ~10 KB at ~900cy HBM latency for 6.3 TB/s).
//
// This version: global_load_lds staging (fire-and-forget into LDS, no VGPR
// writeback) with double-buffered 8KB+8KB chunks and COUNTED vmcnt waits
// (raw s_barrier, never __syncthreads -> never drains vmcnt(0) in-loop).
// In-flight: 16 KB/block x 4 blocks/CU = 64 KB/CU outstanding.
//
// FWHT-8 distributed across lanes: LDS float4 index i (chunk-base 16-aligned)
// has rows of an 8x8 block in bits 1..3 of (i&63) -> 3 shfl_xor butterflies.
// abs-sum is invariant to Hadamard output ordering, matching the reference.

typedef float fvec4 __attribute__((ext_vector_type(4)));

#define CHUNK_F4 512                    // float4 per input per chunk (8 KB)
#define NCHUNKS 48                      // chunks per block
#define GRID 1024                       // 1024*48*512 = 25165824 = n4 exactly

__device__ __forceinline__ float fwht_abssum(fvec4 t, int lane) {
    #pragma unroll
    for (int m = 2; m <= 8; m <<= 1) {
        const bool hi = (lane & m) != 0;
        fvec4 p;
        p.x = __shfl_xor(t.x, m, 64);
        p.y = __shfl_xor(t.y, m, 64);
        p.z = __shfl_xor(t.z, m, 64);
        p.w = __shfl_xor(t.w, m, 64);
        fvec4 add = t + p;
        fvec4 sub = p - t;
        t = hi ? sub : add;
    }
    return fabsf(t.x) + fabsf(t.y) + fabsf(t.z) + fabsf(t.w);
}

__global__ __launch_bounds__(256) void satd_loss_kernel(
        const fvec4* __restrict__ orig, const fvec4* __restrict__ pred,
        float* __restrict__ out) {
    __shared__ fvec4 buf[2][2 * CHUNK_F4];   // [bufsel][orig 512 | pred 512]
    __shared__ float wsum[4];

    const int t = threadIdx.x;
    const int w = t >> 6;                     // wave 0..3
    const int lane = t & 63;
    const int ch0 = blockIdx.x * NCHUNKS;     // this block's first chunk

    float acc = 0.0f;

    // ---- stage: wave w copies its 2x(2x1KB) share of chunk ch into buf[bs]
    auto stage = [&](int ch, int bs) {
        const int cb = ch * CHUNK_F4;         // global f4 base of chunk
        #pragma unroll
        for (int k = 0; k < 2; ++k) {
            const int seg = 2 * w + k;        // 64-float4 segment 0..7
            const fvec4* go = orig + cb + seg * 64 + lane;
            const fvec4* gp = pred + cb + seg * 64 + lane;
            __builtin_amdgcn_global_load_lds(
                (const __attribute__((address_space(1))) void*)go,
                (__attribute__((address_space(3))) void*)&buf[bs][seg * 64],
                16, 0, 0);
            __builtin_amdgcn_global_load_lds(
                (const __attribute__((address_space(1))) void*)gp,
                (__attribute__((address_space(3))) void*)&buf[bs][CHUNK_F4 + seg * 64],
                16, 0, 0);
        }
    };

    stage(ch0, 0);                            // prologue: chunk 0 -> buf0

    for (int c = 0; c < NCHUNKS - 1; ++c) {
        stage(ch0 + c + 1, (c + 1) & 1);      // prefetch next chunk
        // wait only this wave's 4 oldest (chunk c) loads; keep 4 in flight
        asm volatile("s_waitcnt vmcnt(4)" ::: "memory");
        __builtin_amdgcn_s_barrier();
        __builtin_amdgcn_sched_barrier(0);
        {
            const int bs = c & 1;
            fvec4 d0 = buf[bs][t]       - buf[bs][CHUNK_F4 + t];
            fvec4 d1 = buf[bs][t + 256] - buf[bs][CHUNK_F4 + t + 256];
            acc += fwht_abssum(d0, lane);
            acc += fwht_abssum(d1, lane);
        }
        __builtin_amdgcn_s_barrier();         // buf[c&1] free for reuse
        __builtin_amdgcn_sched_barrier(0);
    }

    // epilogue: last chunk
    asm volatile("s_waitcnt vmcnt(0)" ::: "memory");
    __builtin_amdgcn_s_barrier();
    __builtin_amdgcn_sched_barrier(0);
    {
        const int bs = (NCHUNKS - 1) & 1;
        fvec4 d0 = buf[bs][t]       - buf[bs][CHUNK_F4 + t];
        fvec4 d1 = buf[bs][t + 256] - buf[bs][CHUNK_F4 + t + 256];
        acc += fwht_abssum(d0, lane);
        acc += fwht_abssum(d1, lane);
    }

    // wave-64 reduction
    #pragma unroll
    for (int off = 32; off > 0; off >>= 1)
        acc += __shfl_down(acc, off, 64);

    if (lane == 0) wsum[w] = acc;
    __syncthreads();

    if (t == 0) {
        float s = wsum[0] + wsum[1] + wsum[2] + wsum[3];
        atomicAdd(out, s);
    }
}

extern "C" void kernel_launch(void* const* d_in, const int* in_sizes, int n_in,
                              void* d_out, int out_size, void* d_ws, size_t ws_size,
                              hipStream_t stream) {
    const fvec4* orig = (const fvec4*)d_in[0];
    const fvec4* pred = (const fvec4*)d_in[1];
    float* out = (float*)d_out;

    // harness poisons d_out; zero it every call (graph-capturable memset node)
    (void)hipMemsetAsync(out, 0, sizeof(float) * (size_t)out_size, stream);

    satd_loss_kernel<<<GRID, 256, 0, stream>>>(orig, pred, out);
}

// Round 7
// 146.554 us; speedup vs baseline: 1.1827x; 1.0473x over previous
//
#include <hip/hip_runtime.h>

// SATD-style loss: sum(|H8 @ (orig - pred)|) over [524288, 3, 8, 8] fp32 blocks.
// Memory-bound: 805 MB read, scalar out. CHAMPION (R0) structure: each thread
// handles 4 columns (w-half) of one 8x8 channel-block via float4 row loads;
// FWHT-8 along rows in registers; 16 loads in flight per thread.
//
// R0-R6 established: all access-pattern/occupancy/async-staging variants land
// at 5.2-5.5 TB/s effective read BW; this structure is the best measured.

__device__ __forceinline__ float4 f4add(float4 a, float4 b) {
    return make_float4(a.x + b.x, a.y + b.y, a.z + b.z, a.w + b.w);
}
__device__ __forceinline__ float4 f4sub(float4 a, float4 b) {
    return make_float4(a.x - b.x, a.y - b.y, a.z - b.z, a.w - b.w);
}
__device__ __forceinline__ float f4abssum(float4 a) {
    return fabsf(a.x) + fabsf(a.y) + fabsf(a.z) + fabsf(a.w);
}

__global__ __launch_bounds__(256) void satd_loss_kernel(
        const float* __restrict__ orig, const float* __restrict__ pred,
        float* __restrict__ out, int nwork) {
    const int tid = blockIdx.x * blockDim.x + threadIdx.x;
    const int gstride = gridDim.x * blockDim.x;

    float acc = 0.0f;

    for (int i = tid; i < nwork; i += gstride) {
        // work item i -> channel-block (i>>1), column half (i&1)
        const int base = (i >> 1) * 64 + (i & 1) * 4;

        float4 d0, d1, d2, d3, d4, d5, d6, d7;
        {
            const float4* o = reinterpret_cast<const float4*>(orig + base);
            const float4* p = reinterpret_cast<const float4*>(pred + base);
            // rows are 8 floats apart = 2 float4s apart
            d0 = f4sub(o[0],  p[0]);
            d1 = f4sub(o[2],  p[2]);
            d2 = f4sub(o[4],  p[4]);
            d3 = f4sub(o[6],  p[6]);
            d4 = f4sub(o[8],  p[8]);
            d5 = f4sub(o[10], p[10]);
            d6 = f4sub(o[12], p[12]);
            d7 = f4sub(o[14], p[14]);
        }

        // 8-point FWHT along rows (abs-sum is ordering-invariant)
        float4 a0 = f4add(d0, d1), a1 = f4sub(d0, d1);
        float4 a2 = f4add(d2, d3), a3 = f4sub(d2, d3);
        float4 a4 = f4add(d4, d5), a5 = f4sub(d4, d5);
        float4 a6 = f4add(d6, d7), a7 = f4sub(d6, d7);

        float4 b0 = f4add(a0, a2), b2 = f4sub(a0, a2);
        float4 b1 = f4add(a1, a3), b3 = f4sub(a1, a3);
        float4 b4 = f4add(a4, a6), b6 = f4sub(a4, a6);
        float4 b5 = f4add(a5, a7), b7 = f4sub(a5, a7);

        float4 c0 = f4add(b0, b4), c4 = f4sub(b0, b4);
        float4 c1 = f4add(b1, b5), c5 = f4sub(b1, b5);
        float4 c2 = f4add(b2, b6), c6 = f4sub(b2, b6);
        float4 c3 = f4add(b3, b7), c7 = f4sub(b3, b7);

        acc += f4abssum(c0) + f4abssum(c1) + f4abssum(c2) + f4abssum(c3)
             + f4abssum(c4) + f4abssum(c5) + f4abssum(c6) + f4abssum(c7);
    }

    // wave-64 reduction
    #pragma unroll
    for (int off = 32; off > 0; off >>= 1)
        acc += __shfl_down(acc, off, 64);

    __shared__ float wsum[4];
    const int lane = threadIdx.x & 63;
    const int wid  = threadIdx.x >> 6;
    if (lane == 0) wsum[wid] = acc;
    __syncthreads();

    if (threadIdx.x == 0) {
        float s = wsum[0] + wsum[1] + wsum[2] + wsum[3];
        atomicAdd(out, s);
    }
}

extern "C" void kernel_launch(void* const* d_in, const int* in_sizes, int n_in,
                              void* d_out, int out_size, void* d_ws, size_t ws_size,
                              hipStream_t stream) {
    const float* orig = (const float*)d_in[0];
    const float* pred = (const float*)d_in[1];
    float* out = (float*)d_out;

    const int nelem = in_sizes[0];          // 524288*3*64 = 100663296
    const int nwork = nelem / 32;           // 32 elements per work item

    // harness poisons d_out; zero it every call (graph-capturable memset node)
    (void)hipMemsetAsync(out, 0, sizeof(float) * (size_t)out_size, stream);

    const int block = 256;
    int grid = 4096;
    const int needed = (nwork + block - 1) / block;
    if (needed < grid) grid = needed;

    satd_loss_kernel<<<grid, block, 0, stream>>>(orig, pred, out, nwork);
}